// Round 5
// baseline (252.520 us; speedup 1.0000x reference)
//
#include <hip/hip_runtime.h>
#include <math.h>

constexpr int kB = 256;      // batches
constexpr int kT = 261;      // tokens per batch
constexpr int kD = 768;      // dim
constexpr int kC = 5;        // cue tokens
constexpr int kG = 16;       // patch grid
constexpr int kP = 256;      // patches per batch
constexpr int kTok = kT * kD;
constexpr float kTau = 0.03f;   // fp32 screening gap threshold

// ---------------- ws layout (floats) ----------------
// tcb   : 1280*768 @ 0
// u_all : 1280*768 @ 983040
// roi   : 1280*768 @ 1966080
// sims  : 1280*256 @ 2949120

// ============ GEMM: C(1280x768) = A(1280x768) * B + optional bias ============
// 32x64 tile, 256 threads (thread = 2x4), grid (40,12)=480 blocks -> 2 blocks/CU.
// MODE 0: A = cue rows gathered from tokens, B = W^T, +bias -> dstA=tcb, dstB=out rows c
// MODE 1: A = tcb (dense),                   B = W,    no bias -> dstA=u_all
// MODE 2: A = roi (dense),                   B = W^T, +bias -> dstA=out rows 5+c
template<int MODE>
__global__ __launch_bounds__(256)
void gemm_k(const float* __restrict__ tokens, const float* __restrict__ W,
            const float* __restrict__ bvec, const float* __restrict__ Asrc,
            float* __restrict__ dstA, float* __restrict__ dstB)
{
    __shared__ float As[32][34];   // [k][m], pad 34 (8B-aligned float2 rows)
    __shared__ float Bs[32][68];   // [k][n], pad 68 (16B-aligned float4 rows)
    const int mt = blockIdx.x, nt = blockIdx.y;
    const int t = threadIdx.x;
    const int tx = t & 15, ty = t >> 4;      // tx: n-quad (0..15), ty: m-pair (0..15)

    // staging decompositions
    const int ar = t >> 3, aq = t & 7;       // A: m-row (0..31), k-group of 4
    const int br = t >> 2, kq = t & 3;       // B transpose: n-row (0..63), k-group of 8
    const int dr = t >> 3, dq = t & 7;       // B direct: k-row (0..31), n-group of 8

    const int am = mt * 32 + ar;
    const float* __restrict__ Ap = (MODE == 0) ? tokens : Asrc;
    const size_t arow = (MODE == 0)
        ? ((size_t)(am / 5) * kTok + (size_t)(am % 5) * kD)
        : ((size_t)am * kD);

    float4 pa, pb0, pb1;
    auto load_regs = [&](int kc) {
        pa = *(const float4*)&Ap[arow + kc + aq * 4];
        if (MODE == 1) {
            pb0 = *(const float4*)&W[(size_t)(kc + dr) * kD + nt * 64 + dq * 8];
            pb1 = *(const float4*)&W[(size_t)(kc + dr) * kD + nt * 64 + dq * 8 + 4];
        } else {
            pb0 = *(const float4*)&W[(size_t)(nt * 64 + br) * kD + kc + kq * 8];
            pb1 = *(const float4*)&W[(size_t)(nt * 64 + br) * kD + kc + kq * 8 + 4];
        }
    };
    auto write_lds = [&]() {
        As[aq*4+0][ar] = pa.x; As[aq*4+1][ar] = pa.y;
        As[aq*4+2][ar] = pa.z; As[aq*4+3][ar] = pa.w;
        if (MODE == 1) {
            *(float4*)&Bs[dr][dq*8]     = pb0;
            *(float4*)&Bs[dr][dq*8 + 4] = pb1;
        } else {
            Bs[kq*8+0][br] = pb0.x; Bs[kq*8+1][br] = pb0.y;
            Bs[kq*8+2][br] = pb0.z; Bs[kq*8+3][br] = pb0.w;
            Bs[kq*8+4][br] = pb1.x; Bs[kq*8+5][br] = pb1.y;
            Bs[kq*8+6][br] = pb1.z; Bs[kq*8+7][br] = pb1.w;
        }
    };

    float acc[2][4] = {};
    auto compute = [&]() {
        #pragma unroll
        for (int kk = 0; kk < 32; ++kk) {
            const float2 a  = *(const float2*)&As[kk][ty * 2];
            const float4 bb = *(const float4*)&Bs[kk][tx * 4];
            acc[0][0] += a.x*bb.x; acc[0][1] += a.x*bb.y; acc[0][2] += a.x*bb.z; acc[0][3] += a.x*bb.w;
            acc[1][0] += a.y*bb.x; acc[1][1] += a.y*bb.y; acc[1][2] += a.y*bb.z; acc[1][3] += a.y*bb.w;
        }
    };

    load_regs(0);
    write_lds();
    __syncthreads();
    for (int kc = 32; kc < kD; kc += 32) {
        load_regs(kc);          // prefetch next chunk under compute
        compute();
        __syncthreads();
        write_lds();
        __syncthreads();
    }
    compute();

    const int n0 = nt * 64 + tx * 4;
    float4 bv = make_float4(0.f, 0.f, 0.f, 0.f);
    if (MODE != 1) bv = *(const float4*)&bvec[n0];
    #pragma unroll
    for (int mi = 0; mi < 2; ++mi) {
        const int m = mt * 32 + ty * 2 + mi;
        const float4 r = make_float4(acc[mi][0] + bv.x, acc[mi][1] + bv.y,
                                     acc[mi][2] + bv.z, acc[mi][3] + bv.w);
        if (MODE == 0) {
            *(float4*)&dstA[(size_t)m * kD + n0] = r;
            *(float4*)&dstB[((size_t)(m / 5) * 10 + (m % 5)) * kD + n0] = r;
        } else if (MODE == 1) {
            *(float4*)&dstA[(size_t)m * kD + n0] = r;
        } else {
            *(float4*)&dstA[((size_t)(m / 5) * 10 + 5 + (m % 5)) * kD + n0] = r;
        }
    }
}

// ============ K3a: fp32 screen sims, wave-per-patch (coalesced) ============
__global__ __launch_bounds__(512, 4)
void k3a_sims(const float* __restrict__ tokens, const float* __restrict__ u_all,
              float* __restrict__ sims)
{
    const int blk = blockIdx.x;
    const int b = blk >> 1, half = blk & 1;
    const int t = threadIdx.x;
    const int w = t >> 6, lane = t & 63;
    const size_t tb = (size_t)b * kTok;

    float4 u[kC][3];   // per-lane u fragments (12 floats per cue)
    {
        const float* ub = u_all + (size_t)b * kC * kD + lane * 4;
        #pragma unroll
        for (int c = 0; c < kC; ++c)
            #pragma unroll
            for (int k = 0; k < 3; ++k)
                u[c][k] = *(const float4*)&ub[c * kD + k * 256];
    }
    const int n0 = half * 128 + w * 16;
    for (int i = 0; i < 16; ++i) {
        const int n = n0 + i;
        const float* p = &tokens[tb + (size_t)(kC + n) * kD + lane * 4];
        const float4 p0 = *(const float4*)&p[0];     // wave reads contiguous 1KB
        const float4 p1 = *(const float4*)&p[256];
        const float4 p2 = *(const float4*)&p[512];
        float s[kC];
        #pragma unroll
        for (int c = 0; c < kC; ++c) {
            s[c] = p0.x*u[c][0].x + p0.y*u[c][0].y + p0.z*u[c][0].z + p0.w*u[c][0].w
                 + p1.x*u[c][1].x + p1.y*u[c][1].y + p1.z*u[c][1].z + p1.w*u[c][1].w
                 + p2.x*u[c][2].x + p2.y*u[c][2].y + p2.z*u[c][2].z + p2.w*u[c][2].w;
        }
        #pragma unroll
        for (int off = 32; off >= 1; off >>= 1)
            #pragma unroll
            for (int c = 0; c < kC; ++c)
                s[c] += __shfl_xor(s[c], off, 64);
        float v = s[4];
        if (lane == 0) v = s[0]; else if (lane == 1) v = s[1];
        else if (lane == 2) v = s[2]; else if (lane == 3) v = s[3];
        if (lane < kC)
            sims[(size_t)b * (kC * kP) + lane * kP + n] = v;
    }
}

// ============ K3b: top-2 + rare fp64 recheck + ROI means ============
__global__ __launch_bounds__(768, 1)
void k3b_select(const float* __restrict__ tokens, const float* __restrict__ W,
                const float* __restrict__ bvec, const float* __restrict__ sims,
                float* __restrict__ roi)
{
    __shared__ double tcb64[kD];
    __shared__ double u64s[kD];
    __shared__ double s64[kP];
    __shared__ int bestn[kC];
    __shared__ int flags;
    const int b = blockIdx.x, t = threadIdx.x;
    const int w = t >> 6, lane = t & 63;
    const size_t tb = (size_t)b * kTok;

    if (t == 0) flags = 0;
    __syncthreads();

    if (w < kC) {     // top-2 per cue, one wave per cue
        const int c = w;
        const float* sr_ = &sims[(size_t)b * (kC * kP) + c * kP];
        float m1 = -3.4e38f, m2 = -3.4e38f; int i1 = 0;
        #pragma unroll
        for (int k = 0; k < 4; ++k) {
            const int n = lane + k * 64;
            const float v = sr_[n];
            if (v > m1 || (v == m1 && n < i1)) { m2 = m1; m1 = v; i1 = n; }
            else if (v > m2) m2 = v;
        }
        #pragma unroll
        for (int off = 32; off >= 1; off >>= 1) {
            const float om1 = __shfl_xor(m1, off, 64);
            const int   oi1 = __shfl_xor(i1, off, 64);
            const float om2 = __shfl_xor(m2, off, 64);
            float nm2 = fmaxf(m2, om2);
            if (om1 > m1 || (om1 == m1 && oi1 < i1)) { nm2 = fmaxf(nm2, m1); m1 = om1; i1 = oi1; }
            else nm2 = fmaxf(nm2, om1);
            m2 = nm2;
        }
        if (lane == 0) {
            bestn[c] = i1;
            if (m1 - m2 < kTau) atomicOr(&flags, 1 << c);
        }
    }
    __syncthreads();

    // fp64 recheck for flagged cues (block-uniform, expected ~3% of cues)
    for (int c = 0; c < kC; ++c) {
        if (!(flags & (1 << c))) continue;
        {   // tcb64[j] = cue . W[j] + b[j], wave-per-row (coalesced W reads)
            const float* cuep = &tokens[tb + (size_t)c * kD + lane * 4];
            const float4 cf0 = *(const float4*)&cuep[0];
            const float4 cf1 = *(const float4*)&cuep[256];
            const float4 cf2 = *(const float4*)&cuep[512];
            for (int j = w; j < kD; j += 12) {
                const float* wr = &W[(size_t)j * kD + lane * 4];
                const float4 w0 = *(const float4*)&wr[0];
                const float4 w1 = *(const float4*)&wr[256];
                const float4 w2 = *(const float4*)&wr[512];
                double acc = (double)w0.x*cf0.x + (double)w0.y*cf0.y + (double)w0.z*cf0.z + (double)w0.w*cf0.w
                           + (double)w1.x*cf1.x + (double)w1.y*cf1.y + (double)w1.z*cf1.z + (double)w1.w*cf1.w
                           + (double)w2.x*cf2.x + (double)w2.y*cf2.y + (double)w2.z*cf2.z + (double)w2.w*cf2.w;
                #pragma unroll
                for (int off = 32; off >= 1; off >>= 1)
                    acc += __shfl_xor(acc, off, 64);
                if (lane == 0) tcb64[j] = acc + (double)bvec[j];
            }
        }
        __syncthreads();
        {   // u64[i] = sum_j tcb64[j] * W[j][i]  (coalesced over i)
            double acc = 0.0;
            for (int j = 0; j < kD; ++j)
                acc += tcb64[j] * (double)W[(size_t)j * kD + t];
            u64s[t] = acc;
        }
        __syncthreads();
        {   // fp64 sims, wave-per-patch
            for (int n = w; n < kP; n += 12) {
                const float* p = &tokens[tb + (size_t)(kC + n) * kD + lane * 4];
                const float4 p0 = *(const float4*)&p[0];
                const float4 p1 = *(const float4*)&p[256];
                const float4 p2 = *(const float4*)&p[512];
                const double* ud = &u64s[lane * 4];
                double acc = (double)p0.x*ud[0]   + (double)p0.y*ud[1]   + (double)p0.z*ud[2]   + (double)p0.w*ud[3]
                           + (double)p1.x*ud[256] + (double)p1.y*ud[257] + (double)p1.z*ud[258] + (double)p1.w*ud[259]
                           + (double)p2.x*ud[512] + (double)p2.y*ud[513] + (double)p2.z*ud[514] + (double)p2.w*ud[515];
                #pragma unroll
                for (int off = 32; off >= 1; off >>= 1)
                    acc += __shfl_xor(acc, off, 64);
                if (lane == 0) s64[n] = acc;
            }
        }
        __syncthreads();
        if (w == 0) {   // fp64 argmax, first-index tie-break
            double best = -1.0e300; int bi = 0;
            #pragma unroll
            for (int k = 0; k < 4; ++k) {
                const int n = lane + k * 64;
                const double v = s64[n];
                if (v > best || (v == best && n < bi)) { best = v; bi = n; }
            }
            #pragma unroll
            for (int off = 32; off >= 1; off >>= 1) {
                const double v2 = __shfl_xor(best, off, 64);
                const int    i2 = __shfl_xor(bi, off, 64);
                if (v2 > best || (v2 == best && i2 < bi)) { best = v2; bi = i2; }
            }
            if (lane == 0) bestn[c] = bi;
        }
        __syncthreads();
    }

    {   // ROI means (coalesced over d = t)
        const int d = t;
        #pragma unroll
        for (int c = 0; c < kC; ++c) {
            const int nn = bestn[c];
            const int h = nn >> 4, ww = nn & 15;
            const int rlo = max(h - 1, 0), rhi = min(h + 1, kG - 1);
            const int clo = max(ww - 1, 0), chi = min(ww + 1, kG - 1);
            float sum = 0.f;
            for (int rr = rlo; rr <= rhi; ++rr)
                for (int cc = clo; cc <= chi; ++cc)
                    sum += tokens[tb + (size_t)(kC + rr * kG + cc) * kD + d];
            roi[((size_t)b * kC + c) * kD + d] = sum / (float)((rhi - rlo + 1) * (chi - clo + 1));
        }
    }
}

// ============ K5: row-wise L2 normalize (in-place on out) ============
__global__ __launch_bounds__(256)
void k5_norm(float* __restrict__ out)
{
    __shared__ float wsum[4];
    const int row = blockIdx.x, t = threadIdx.x;
    float* p = out + (size_t)row * kD;
    const float x0 = p[t], x1 = p[t + 256], x2 = p[t + 512];
    float ss = x0 * x0 + x1 * x1 + x2 * x2;
    #pragma unroll
    for (int off = 32; off >= 1; off >>= 1) ss += __shfl_down(ss, off, 64);
    if ((t & 63) == 0) wsum[t >> 6] = ss;
    __syncthreads();
    const float tot = wsum[0] + wsum[1] + wsum[2] + wsum[3];
    const float nrm = fmaxf(sqrtf(tot), 1e-12f);
    p[t] = x0 / nrm; p[t + 256] = x1 / nrm; p[t + 512] = x2 / nrm;
}

extern "C" void kernel_launch(void* const* d_in, const int* in_sizes, int n_in,
                              void* d_out, int out_size, void* d_ws, size_t ws_size,
                              hipStream_t stream) {
    const float* tokens = (const float*)d_in[0];
    const float* W      = (const float*)d_in[1];
    const float* bvec   = (const float*)d_in[2];
    float* out = (float*)d_out;
    float* ws = (float*)d_ws;
    float* tcb   = ws;
    float* u_all = ws + 983040;
    float* roi   = ws + 1966080;
    float* sims  = ws + 2949120;

    gemm_k<0><<<dim3(40, 12), 256, 0, stream>>>(tokens, W, bvec, nullptr, tcb, out);
    gemm_k<1><<<dim3(40, 12), 256, 0, stream>>>(tokens, W, bvec, tcb, u_all, nullptr);
    k3a_sims<<<dim3(512), 512, 0, stream>>>(tokens, u_all, sims);
    k3b_select<<<dim3(256), 768, 0, stream>>>(tokens, W, bvec, sims, roi);
    gemm_k<2><<<dim3(40, 12), 256, 0, stream>>>(tokens, W, bvec, roi, out, nullptr);
    k5_norm<<<dim3(2560), 256, 0, stream>>>(out);
}

// Round 6
// 188.745 us; speedup vs baseline: 1.3379x; 1.3379x over previous
//
#include <hip/hip_runtime.h>
#include <math.h>

constexpr int kB = 256;      // batches
constexpr int kT = 261;      // tokens per batch
constexpr int kD = 768;      // dim
constexpr int kC = 5;        // cue tokens
constexpr int kG = 16;       // patch grid
constexpr int kP = 256;      // patches per batch
constexpr int kTok = kT * kD;
constexpr float kTau = 0.03f;   // fp32/bf16-split screening gap threshold

typedef short short8v __attribute__((ext_vector_type(8)));
typedef float f32x4 __attribute__((ext_vector_type(4)));
typedef unsigned short ushort_t;

// bf16 round-to-nearest-even split helpers
__device__ inline ushort_t f2bf(float x) {
    unsigned int u = __float_as_uint(x);
    unsigned int r = (u + 0x7FFFu + ((u >> 16) & 1u)) >> 16;
    return (ushort_t)r;
}
__device__ inline float bf2f(ushort_t h) { return __uint_as_float(((unsigned int)h) << 16); }

// ---------------- ws layout ----------------
// floats: tcb @0 (1280*768), u_all @983040, roi @1966080
// ushorts @ float-offset 2949120: Wb_hi, Wb_lo, Wt_hi, Wt_lo (each 768*768)

// ============ Kprep: split W into bf16 hi/lo, direct + transposed layouts ============
__global__ __launch_bounds__(256)
void kprep(const float* __restrict__ W,
           ushort_t* __restrict__ Wb_hi, ushort_t* __restrict__ Wb_lo,
           ushort_t* __restrict__ Wt_hi, ushort_t* __restrict__ Wt_lo)
{
    __shared__ ushort_t Lhi[32][36], Llo[32][36];
    const int blk = blockIdx.x, tr = blk / 24, tc = blk % 24;
    const int t = threadIdx.x, r = t >> 3, q = t & 7;
    const int row = tr * 32 + r, col = tc * 32 + q * 4;
    const float4 v = *(const float4*)&W[(size_t)row * kD + col];
    const ushort_t h0 = f2bf(v.x), h1 = f2bf(v.y), h2 = f2bf(v.z), h3 = f2bf(v.w);
    const ushort_t l0 = f2bf(v.x - bf2f(h0)), l1 = f2bf(v.y - bf2f(h1));
    const ushort_t l2 = f2bf(v.z - bf2f(h2)), l3 = f2bf(v.w - bf2f(h3));
    *(ushort4*)&Wb_hi[(size_t)row * kD + col] = make_ushort4(h0, h1, h2, h3);
    *(ushort4*)&Wb_lo[(size_t)row * kD + col] = make_ushort4(l0, l1, l2, l3);
    Lhi[r][q*4+0] = h0; Lhi[r][q*4+1] = h1; Lhi[r][q*4+2] = h2; Lhi[r][q*4+3] = h3;
    Llo[r][q*4+0] = l0; Llo[r][q*4+1] = l1; Llo[r][q*4+2] = l2; Llo[r][q*4+3] = l3;
    __syncthreads();
    // Wt[d][j] = W[j][d]
    const size_t orow = (size_t)(tc * 32 + r) * kD + tr * 32 + q * 4;
    *(ushort4*)&Wt_hi[orow] = make_ushort4(Lhi[q*4+0][r], Lhi[q*4+1][r], Lhi[q*4+2][r], Lhi[q*4+3][r]);
    *(ushort4*)&Wt_lo[orow] = make_ushort4(Llo[q*4+0][r], Llo[q*4+1][r], Llo[q*4+2][r], Llo[q*4+3][r]);
}

// ============ Kmm: C(1280x768) = A * B via bf16 hi/lo split MFMA ============
// B pre-split in [n][k] layout (Bsrc[n*768+k] = B[k][n]).
// MODE 0: A = cue rows (tokens), B = W^T (Bsrc=Wb), +bias -> dstA=tcb, dstB=out rows c
// MODE 1: A = tcb,               B = W   (Bsrc=Wt), no bias -> dstA=u_all
// MODE 2: A = roi,               B = W^T (Bsrc=Wb), +bias -> dstA=out rows 5+c
template<int MODE>
__global__ __launch_bounds__(256)
void kmm(const float* __restrict__ tokens,
         const ushort_t* __restrict__ Bhi, const ushort_t* __restrict__ Blo,
         const float* __restrict__ bvec, const float* __restrict__ Asrc,
         float* __restrict__ dstA, float* __restrict__ dstB)
{
    __shared__ ushort_t Ah[32][40], Al[32][40];     // padded: row stride 80B (16B-aligned, 2-way banks)
    __shared__ ushort_t Bh[64][40], Bl[64][40];
    const int mt = blockIdx.x, nt = blockIdx.y, t = threadIdx.x;
    const int w = t >> 6, l = t & 63;
    const int ln = l & 15, kq = l >> 4;             // frag: m/n-local, k-block
    const int mf = w & 1, nh = w >> 1;              // wave -> (m-frag, n-half)
    const int ar = t >> 3, aq = t & 7;              // A staging: row(32), 4-float group
    const int br = t >> 2, bq = t & 3;              // B staging: row(64), 8-bf16 group

    const int am = mt * 32 + ar;
    const float* __restrict__ Ap = (MODE == 0) ? tokens : Asrc;
    const size_t arow = (MODE == 0)
        ? ((size_t)(am / 5) * kTok + (size_t)(am % 5) * kD)
        : ((size_t)am * kD);
    const size_t brow = (size_t)(nt * 64 + br) * kD;

    float4 pa; uint4 pbh, pbl;
    auto load_regs = [&](int kc) {
        pa  = *(const float4*)&Ap[arow + kc + aq * 4];
        pbh = *(const uint4*)&Bhi[brow + kc + bq * 8];
        pbl = *(const uint4*)&Blo[brow + kc + bq * 8];
    };
    auto write_lds = [&]() {
        const ushort_t h0 = f2bf(pa.x), h1 = f2bf(pa.y), h2 = f2bf(pa.z), h3 = f2bf(pa.w);
        const ushort_t a0 = f2bf(pa.x - bf2f(h0)), a1 = f2bf(pa.y - bf2f(h1));
        const ushort_t a2 = f2bf(pa.z - bf2f(h2)), a3 = f2bf(pa.w - bf2f(h3));
        *(ushort4*)&Ah[ar][aq * 4] = make_ushort4(h0, h1, h2, h3);
        *(ushort4*)&Al[ar][aq * 4] = make_ushort4(a0, a1, a2, a3);
        *(uint4*)&Bh[br][bq * 8] = pbh;
        *(uint4*)&Bl[br][bq * 8] = pbl;
    };

    f32x4 acc0 = {0.f, 0.f, 0.f, 0.f}, acc1 = {0.f, 0.f, 0.f, 0.f};
    auto compute = [&]() {
        const short8v ah  = *(const short8v*)&Ah[mf * 16 + ln][kq * 8];
        const short8v al_ = *(const short8v*)&Al[mf * 16 + ln][kq * 8];
        const short8v bh0 = *(const short8v*)&Bh[nh * 32 + ln][kq * 8];
        const short8v bl0 = *(const short8v*)&Bl[nh * 32 + ln][kq * 8];
        const short8v bh1 = *(const short8v*)&Bh[nh * 32 + 16 + ln][kq * 8];
        const short8v bl1 = *(const short8v*)&Bl[nh * 32 + 16 + ln][kq * 8];
        acc0 = __builtin_amdgcn_mfma_f32_16x16x32_bf16(al_, bh0, acc0, 0, 0, 0);
        acc0 = __builtin_amdgcn_mfma_f32_16x16x32_bf16(ah,  bl0, acc0, 0, 0, 0);
        acc0 = __builtin_amdgcn_mfma_f32_16x16x32_bf16(ah,  bh0, acc0, 0, 0, 0);
        acc1 = __builtin_amdgcn_mfma_f32_16x16x32_bf16(al_, bh1, acc1, 0, 0, 0);
        acc1 = __builtin_amdgcn_mfma_f32_16x16x32_bf16(ah,  bl1, acc1, 0, 0, 0);
        acc1 = __builtin_amdgcn_mfma_f32_16x16x32_bf16(ah,  bh1, acc1, 0, 0, 0);
    };

    load_regs(0);
    write_lds();
    __syncthreads();
    for (int kc = 32; kc < kD; kc += 32) {
        load_regs(kc);          // prefetch next chunk under compute
        compute();
        __syncthreads();
        write_lds();
        __syncthreads();
    }
    compute();

    // epilogue: C/D layout col=lane&15, row=(lane>>4)*4+reg
    #pragma unroll
    for (int nf = 0; nf < 2; ++nf) {
        const int col = nt * 64 + nh * 32 + nf * 16 + ln;
        const float bb = (MODE != 1) ? bvec[col] : 0.f;
        const f32x4 acc = nf ? acc1 : acc0;
        #pragma unroll
        for (int r = 0; r < 4; ++r) {
            const int row = mt * 32 + mf * 16 + kq * 4 + r;
            const float val = acc[r] + bb;
            if (MODE == 0) {
                dstA[(size_t)row * kD + col] = val;
                dstB[((size_t)(row / 5) * 10 + (row % 5)) * kD + col] = val;
            } else if (MODE == 1) {
                dstA[(size_t)row * kD + col] = val;
            } else {
                dstA[((size_t)(row / 5) * 10 + 5 + (row % 5)) * kD + col] = val;
            }
        }
    }
}

// ============ Ksel: sims (fp32 screen) + top2 + rare fp64 recheck + ROI ============
__global__ __launch_bounds__(1024, 1)
void ksel(const float* __restrict__ tokens, const float* __restrict__ W,
          const float* __restrict__ bvec, const float* __restrict__ u_all,
          float* __restrict__ roi)
{
    __shared__ float  simsL[kC][kP];
    __shared__ double tcb64[kD], u64s[kD];
    __shared__ double s64[kP];
    __shared__ int bestn[kC];
    __shared__ int flags;
    const int b = blockIdx.x, t = threadIdx.x;
    const int w = t >> 6, lane = t & 63;
    const size_t tb = (size_t)b * kTok;
    if (t == 0) flags = 0;

    {   // phase 1: fp32 sims, wave-per-patch (16 waves x 16 patches)
        float4 u[kC][3];
        const float* ub = u_all + (size_t)b * kC * kD + lane * 4;
        #pragma unroll
        for (int c = 0; c < kC; ++c)
            #pragma unroll
            for (int k = 0; k < 3; ++k)
                u[c][k] = *(const float4*)&ub[c * kD + k * 256];
        for (int i = 0; i < 16; ++i) {
            const int n = w * 16 + i;
            const float* p = &tokens[tb + (size_t)(kC + n) * kD + lane * 4];
            const float4 p0 = *(const float4*)&p[0];
            const float4 p1 = *(const float4*)&p[256];
            const float4 p2 = *(const float4*)&p[512];
            float s[kC];
            #pragma unroll
            for (int c = 0; c < kC; ++c) {
                s[c] = p0.x*u[c][0].x + p0.y*u[c][0].y + p0.z*u[c][0].z + p0.w*u[c][0].w
                     + p1.x*u[c][1].x + p1.y*u[c][1].y + p1.z*u[c][1].z + p1.w*u[c][1].w
                     + p2.x*u[c][2].x + p2.y*u[c][2].y + p2.z*u[c][2].z + p2.w*u[c][2].w;
            }
            #pragma unroll
            for (int off = 32; off >= 1; off >>= 1)
                #pragma unroll
                for (int c = 0; c < kC; ++c)
                    s[c] += __shfl_xor(s[c], off, 64);
            float v = s[4];
            if (lane == 0) v = s[0]; else if (lane == 1) v = s[1];
            else if (lane == 2) v = s[2]; else if (lane == 3) v = s[3];
            if (lane < kC) simsL[lane][n] = v;
        }
    }
    __syncthreads();

    if (w < kC) {   // top-2 per cue (first-index tie-break)
        const int c = w;
        float m1 = -3.4e38f, m2 = -3.4e38f; int i1 = 0;
        #pragma unroll
        for (int k = 0; k < 4; ++k) {
            const int n = lane + k * 64;
            const float v = simsL[c][n];
            if (v > m1 || (v == m1 && n < i1)) { m2 = m1; m1 = v; i1 = n; }
            else if (v > m2) m2 = v;
        }
        #pragma unroll
        for (int off = 32; off >= 1; off >>= 1) {
            const float om1 = __shfl_xor(m1, off, 64);
            const int   oi1 = __shfl_xor(i1, off, 64);
            const float om2 = __shfl_xor(m2, off, 64);
            float nm2 = fmaxf(m2, om2);
            if (om1 > m1 || (om1 == m1 && oi1 < i1)) { nm2 = fmaxf(nm2, m1); m1 = om1; i1 = oi1; }
            else nm2 = fmaxf(nm2, om1);
            m2 = nm2;
        }
        if (lane == 0) {
            bestn[c] = i1;
            if (m1 - m2 < kTau) atomicOr(&flags, 1 << c);
        }
    }
    __syncthreads();

    // fp64 recheck for flagged cues (block-uniform, rare)
    for (int c = 0; c < kC; ++c) {
        if (!(flags & (1 << c))) continue;
        {   // tcb64[j] = cue . W[j] + b[j]
            const float* cuep = &tokens[tb + (size_t)c * kD + lane * 4];
            const float4 cf0 = *(const float4*)&cuep[0];
            const float4 cf1 = *(const float4*)&cuep[256];
            const float4 cf2 = *(const float4*)&cuep[512];
            for (int j = w; j < kD; j += 16) {
                const float* wr = &W[(size_t)j * kD + lane * 4];
                const float4 w0 = *(const float4*)&wr[0];
                const float4 w1 = *(const float4*)&wr[256];
                const float4 w2 = *(const float4*)&wr[512];
                double acc = (double)w0.x*cf0.x + (double)w0.y*cf0.y + (double)w0.z*cf0.z + (double)w0.w*cf0.w
                           + (double)w1.x*cf1.x + (double)w1.y*cf1.y + (double)w1.z*cf1.z + (double)w1.w*cf1.w
                           + (double)w2.x*cf2.x + (double)w2.y*cf2.y + (double)w2.z*cf2.z + (double)w2.w*cf2.w;
                #pragma unroll
                for (int off = 32; off >= 1; off >>= 1)
                    acc += __shfl_xor(acc, off, 64);
                if (lane == 0) tcb64[j] = acc + (double)bvec[j];
            }
        }
        __syncthreads();
        if (t < kD) {   // u64[i] = sum_j tcb64[j] * W[j][i]
            double acc = 0.0;
            for (int j = 0; j < kD; ++j)
                acc += tcb64[j] * (double)W[(size_t)j * kD + t];
            u64s[t] = acc;
        }
        __syncthreads();
        for (int n = w; n < kP; n += 16) {   // fp64 sims, wave-per-patch
            const float* p = &tokens[tb + (size_t)(kC + n) * kD + lane * 4];
            const float4 p0 = *(const float4*)&p[0];
            const float4 p1 = *(const float4*)&p[256];
            const float4 p2 = *(const float4*)&p[512];
            const double* ud = &u64s[lane * 4];
            double acc = (double)p0.x*ud[0]   + (double)p0.y*ud[1]   + (double)p0.z*ud[2]   + (double)p0.w*ud[3]
                       + (double)p1.x*ud[256] + (double)p1.y*ud[257] + (double)p1.z*ud[258] + (double)p1.w*ud[259]
                       + (double)p2.x*ud[512] + (double)p2.y*ud[513] + (double)p2.z*ud[514] + (double)p2.w*ud[515];
            #pragma unroll
            for (int off = 32; off >= 1; off >>= 1)
                acc += __shfl_xor(acc, off, 64);
            if (lane == 0) s64[n] = acc;
        }
        __syncthreads();
        if (w == 0) {   // fp64 argmax, first-index tie-break
            double best = -1.0e300; int bi = 0;
            #pragma unroll
            for (int k = 0; k < 4; ++k) {
                const int n = lane + k * 64;
                const double v = s64[n];
                if (v > best || (v == best && n < bi)) { best = v; bi = n; }
            }
            #pragma unroll
            for (int off = 32; off >= 1; off >>= 1) {
                const double v2 = __shfl_xor(best, off, 64);
                const int    i2 = __shfl_xor(bi, off, 64);
                if (v2 > best || (v2 == best && i2 < bi)) { best = v2; bi = i2; }
            }
            if (lane == 0) bestn[c] = bi;
        }
        __syncthreads();
    }

    if (t < kD) {   // ROI means (coalesced over d = t)
        const int d = t;
        #pragma unroll
        for (int c = 0; c < kC; ++c) {
            const int nn = bestn[c];
            const int h = nn >> 4, ww = nn & 15;
            const int rlo = max(h - 1, 0), rhi = min(h + 1, kG - 1);
            const int clo = max(ww - 1, 0), chi = min(ww + 1, kG - 1);
            float sum = 0.f;
            for (int rr = rlo; rr <= rhi; ++rr)
                for (int cc = clo; cc <= chi; ++cc)
                    sum += tokens[tb + (size_t)(kC + rr * kG + cc) * kD + d];
            roi[((size_t)b * kC + c) * kD + d] = sum / (float)((rhi - rlo + 1) * (chi - clo + 1));
        }
    }
}

// ============ Knorm: row-wise L2 normalize (in-place on out) ============
__global__ __launch_bounds__(256)
void knorm(float* __restrict__ out)
{
    __shared__ float wsum[4];
    const int row = blockIdx.x, t = threadIdx.x;
    float* p = out + (size_t)row * kD;
    const float x0 = p[t], x1 = p[t + 256], x2 = p[t + 512];
    float ss = x0 * x0 + x1 * x1 + x2 * x2;
    #pragma unroll
    for (int off = 32; off >= 1; off >>= 1) ss += __shfl_down(ss, off, 64);
    if ((t & 63) == 0) wsum[t >> 6] = ss;
    __syncthreads();
    const float tot = wsum[0] + wsum[1] + wsum[2] + wsum[3];
    const float nrm = fmaxf(sqrtf(tot), 1e-12f);
    p[t] = x0 / nrm; p[t + 256] = x1 / nrm; p[t + 512] = x2 / nrm;
}

extern "C" void kernel_launch(void* const* d_in, const int* in_sizes, int n_in,
                              void* d_out, int out_size, void* d_ws, size_t ws_size,
                              hipStream_t stream) {
    const float* tokens = (const float*)d_in[0];
    const float* W      = (const float*)d_in[1];
    const float* bvec   = (const float*)d_in[2];
    float* out = (float*)d_out;
    float* ws = (float*)d_ws;
    float* tcb   = ws;
    float* u_all = ws + 983040;
    float* roi   = ws + 1966080;
    ushort_t* wsb = (ushort_t*)(ws + 2949120);
    ushort_t* Wb_hi = wsb;
    ushort_t* Wb_lo = wsb + 589824;
    ushort_t* Wt_hi = wsb + 1179648;
    ushort_t* Wt_lo = wsb + 1769472;

    kprep<<<dim3(576), 256, 0, stream>>>(W, Wb_hi, Wb_lo, Wt_hi, Wt_lo);
    kmm<0><<<dim3(40, 12), 256, 0, stream>>>(tokens, Wb_hi, Wb_lo, bvec, nullptr, tcb, out);
    kmm<1><<<dim3(40, 12), 256, 0, stream>>>(tokens, Wt_hi, Wt_lo, bvec, tcb, u_all, nullptr);
    ksel<<<dim3(256), 1024, 0, stream>>>(tokens, W, bvec, u_all, roi);
    kmm<2><<<dim3(40, 12), 256, 0, stream>>>(tokens, Wb_hi, Wb_lo, bvec, roi, out, nullptr);
    knorm<<<dim3(2560), 256, 0, stream>>>(out);
}

// Round 7
// 182.482 us; speedup vs baseline: 1.3838x; 1.0343x over previous
//
#include <hip/hip_runtime.h>
#include <math.h>

constexpr int kB = 256;      // batches
constexpr int kT = 261;      // tokens per batch
constexpr int kD = 768;      // dim
constexpr int kC = 5;        // cue tokens
constexpr int kG = 16;       // patch grid
constexpr int kP = 256;      // patches per batch
constexpr int kTok = kT * kD;
constexpr float kTau = 0.03f;   // screening gap threshold (screen err ≲ 1e-3)

typedef short short8v __attribute__((ext_vector_type(8)));
typedef float f32x4 __attribute__((ext_vector_type(4)));
typedef unsigned short ushort_t;

// bf16 round-to-nearest-even split helpers
__device__ inline ushort_t f2bf(float x) {
    unsigned int u = __float_as_uint(x);
    unsigned int r = (u + 0x7FFFu + ((u >> 16) & 1u)) >> 16;
    return (ushort_t)r;
}
__device__ inline float bf2f(ushort_t h) { return __uint_as_float(((unsigned int)h) << 16); }

// ---------------- ws layout ----------------
// floats: tcb @0 (1280*768), u_all @983040, roi @1966080
// ushorts @ float-offset 2949120: Wb_hi, Wb_lo, Wt_hi, Wt_lo (each 768*768)

// ============ Kprep: split W into bf16 hi/lo, direct + transposed layouts ============
__global__ __launch_bounds__(256)
void kprep(const float* __restrict__ W,
           ushort_t* __restrict__ Wb_hi, ushort_t* __restrict__ Wb_lo,
           ushort_t* __restrict__ Wt_hi, ushort_t* __restrict__ Wt_lo)
{
    __shared__ ushort_t Lhi[32][36], Llo[32][36];
    const int blk = blockIdx.x, tr = blk / 24, tc = blk % 24;
    const int t = threadIdx.x, r = t >> 3, q = t & 7;
    const int row = tr * 32 + r, col = tc * 32 + q * 4;
    const float4 v = *(const float4*)&W[(size_t)row * kD + col];
    const ushort_t h0 = f2bf(v.x), h1 = f2bf(v.y), h2 = f2bf(v.z), h3 = f2bf(v.w);
    const ushort_t l0 = f2bf(v.x - bf2f(h0)), l1 = f2bf(v.y - bf2f(h1));
    const ushort_t l2 = f2bf(v.z - bf2f(h2)), l3 = f2bf(v.w - bf2f(h3));
    *(ushort4*)&Wb_hi[(size_t)row * kD + col] = make_ushort4(h0, h1, h2, h3);
    *(ushort4*)&Wb_lo[(size_t)row * kD + col] = make_ushort4(l0, l1, l2, l3);
    Lhi[r][q*4+0] = h0; Lhi[r][q*4+1] = h1; Lhi[r][q*4+2] = h2; Lhi[r][q*4+3] = h3;
    Llo[r][q*4+0] = l0; Llo[r][q*4+1] = l1; Llo[r][q*4+2] = l2; Llo[r][q*4+3] = l3;
    __syncthreads();
    // Wt[d][j] = W[j][d]
    const size_t orow = (size_t)(tc * 32 + r) * kD + tr * 32 + q * 4;
    *(ushort4*)&Wt_hi[orow] = make_ushort4(Lhi[q*4+0][r], Lhi[q*4+1][r], Lhi[q*4+2][r], Lhi[q*4+3][r]);
    *(ushort4*)&Wt_lo[orow] = make_ushort4(Llo[q*4+0][r], Llo[q*4+1][r], Llo[q*4+2][r], Llo[q*4+3][r]);
}

// ============ Kmm: C(1280x768) = A * B via bf16 hi/lo split MFMA ============
template<int MODE>
__global__ __launch_bounds__(256)
void kmm(const float* __restrict__ tokens,
         const ushort_t* __restrict__ Bhi, const ushort_t* __restrict__ Blo,
         const float* __restrict__ bvec, const float* __restrict__ Asrc,
         float* __restrict__ dstA, float* __restrict__ dstB)
{
    __shared__ ushort_t Ah[32][40], Al[32][40];
    __shared__ ushort_t Bh[64][40], Bl[64][40];
    const int mt = blockIdx.x, nt = blockIdx.y, t = threadIdx.x;
    const int w = t >> 6, l = t & 63;
    const int ln = l & 15, kq = l >> 4;
    const int mf = w & 1, nh = w >> 1;
    const int ar = t >> 3, aq = t & 7;
    const int br = t >> 2, bq = t & 3;

    const int am = mt * 32 + ar;
    const float* __restrict__ Ap = (MODE == 0) ? tokens : Asrc;
    const size_t arow = (MODE == 0)
        ? ((size_t)(am / 5) * kTok + (size_t)(am % 5) * kD)
        : ((size_t)am * kD);
    const size_t brow = (size_t)(nt * 64 + br) * kD;

    float4 pa; uint4 pbh, pbl;
    auto load_regs = [&](int kc) {
        pa  = *(const float4*)&Ap[arow + kc + aq * 4];
        pbh = *(const uint4*)&Bhi[brow + kc + bq * 8];
        pbl = *(const uint4*)&Blo[brow + kc + bq * 8];
    };
    auto write_lds = [&]() {
        const ushort_t h0 = f2bf(pa.x), h1 = f2bf(pa.y), h2 = f2bf(pa.z), h3 = f2bf(pa.w);
        const ushort_t a0 = f2bf(pa.x - bf2f(h0)), a1 = f2bf(pa.y - bf2f(h1));
        const ushort_t a2 = f2bf(pa.z - bf2f(h2)), a3 = f2bf(pa.w - bf2f(h3));
        *(ushort4*)&Ah[ar][aq * 4] = make_ushort4(h0, h1, h2, h3);
        *(ushort4*)&Al[ar][aq * 4] = make_ushort4(a0, a1, a2, a3);
        *(uint4*)&Bh[br][bq * 8] = pbh;
        *(uint4*)&Bl[br][bq * 8] = pbl;
    };

    f32x4 acc0 = {0.f, 0.f, 0.f, 0.f}, acc1 = {0.f, 0.f, 0.f, 0.f};
    auto compute = [&]() {
        const short8v ah  = *(const short8v*)&Ah[mf * 16 + ln][kq * 8];
        const short8v al_ = *(const short8v*)&Al[mf * 16 + ln][kq * 8];
        const short8v bh0 = *(const short8v*)&Bh[nh * 32 + ln][kq * 8];
        const short8v bl0 = *(const short8v*)&Bl[nh * 32 + ln][kq * 8];
        const short8v bh1 = *(const short8v*)&Bh[nh * 32 + 16 + ln][kq * 8];
        const short8v bl1 = *(const short8v*)&Bl[nh * 32 + 16 + ln][kq * 8];
        acc0 = __builtin_amdgcn_mfma_f32_16x16x32_bf16(al_, bh0, acc0, 0, 0, 0);
        acc0 = __builtin_amdgcn_mfma_f32_16x16x32_bf16(ah,  bl0, acc0, 0, 0, 0);
        acc0 = __builtin_amdgcn_mfma_f32_16x16x32_bf16(ah,  bh0, acc0, 0, 0, 0);
        acc1 = __builtin_amdgcn_mfma_f32_16x16x32_bf16(al_, bh1, acc1, 0, 0, 0);
        acc1 = __builtin_amdgcn_mfma_f32_16x16x32_bf16(ah,  bl1, acc1, 0, 0, 0);
        acc1 = __builtin_amdgcn_mfma_f32_16x16x32_bf16(ah,  bh1, acc1, 0, 0, 0);
    };

    load_regs(0);
    write_lds();
    __syncthreads();
    for (int kc = 32; kc < kD; kc += 32) {
        load_regs(kc);
        compute();
        __syncthreads();
        write_lds();
        __syncthreads();
    }
    compute();

    #pragma unroll
    for (int nf = 0; nf < 2; ++nf) {
        const int col = nt * 64 + nh * 32 + nf * 16 + ln;
        const float bb = (MODE != 1) ? bvec[col] : 0.f;
        const f32x4 acc = nf ? acc1 : acc0;
        #pragma unroll
        for (int r = 0; r < 4; ++r) {
            const int row = mt * 32 + mf * 16 + kq * 4 + r;
            const float val = acc[r] + bb;
            if (MODE == 0) {
                dstA[(size_t)row * kD + col] = val;
                dstB[((size_t)(row / 5) * 10 + (row % 5)) * kD + col] = val;
            } else if (MODE == 1) {
                dstA[(size_t)row * kD + col] = val;
            } else {
                dstA[((size_t)(row / 5) * 10 + 5 + (row % 5)) * kD + col] = val;
            }
        }
    }
}

// ============ Ksel: MFMA sims screen + top2 + rare fp64 recheck + ROI ============
// 1 block per batch, 1024 threads (16 waves). sims = U(5x768,pad16) . P^T via
// bf16 hi/lo MFMA; patches staged per K=32 chunk in double-buffered LDS.
__global__ __launch_bounds__(1024, 1)
void ksel(const float* __restrict__ tokens, const float* __restrict__ W,
          const float* __restrict__ bvec, const float* __restrict__ u_all,
          float* __restrict__ roi)
{
    __shared__ ushort_t Ph[2][256][40], Pl[2][256][40];   // patch chunk bf16 hi/lo, [n][k]
    __shared__ ushort_t Uh[6][776], Ul[6][776];           // u bf16 hi/lo, row 5 = zeros
    __shared__ float  simsL[kC][kP];
    __shared__ double tcb64[kD], u64s[kD];
    __shared__ double s64[kP];
    __shared__ int bestn[kC];
    __shared__ int flags;

    const int b = blockIdx.x, t = threadIdx.x;
    const int w = t >> 6, lane = t & 63;
    const int ln = lane & 15, kq = lane >> 4;
    const size_t tb = (size_t)b * kTok;
    if (t == 0) flags = 0;

    // ---- phase 0: u -> bf16 hi/lo LDS (rows 5..15 of A read zeroed row 5) ----
    if (t < kD) {
        const float* ub = u_all + (size_t)b * kC * kD;
        #pragma unroll
        for (int c = 0; c < kC; ++c) {
            const float v = ub[(size_t)c * kD + t];
            const ushort_t h = f2bf(v);
            Uh[c][t] = h;
            Ul[c][t] = f2bf(v - bf2f(h));
        }
    }
    if (t < 776) { Uh[kC][t] = 0; Ul[kC][t] = 0; }

    // ---- phase 1: sims via MFMA over 24 chunks of K=32 ----
    const int sr = t >> 3, sq = t & 7;         // staging: rows sr, sr+128; k-sub sq
    const size_t prow0 = tb + (size_t)(kC + sr) * kD + sq * 4;
    const size_t prow1 = tb + (size_t)(kC + sr + 128) * kD + sq * 4;
    float4 fa, fb;
    auto load_regs = [&](int chunk) {
        fa = *(const float4*)&tokens[prow0 + chunk * 32];
        fb = *(const float4*)&tokens[prow1 + chunk * 32];
    };
    auto write_lds = [&](int buf) {
        ushort_t h0 = f2bf(fa.x), h1 = f2bf(fa.y), h2 = f2bf(fa.z), h3 = f2bf(fa.w);
        *(ushort4*)&Ph[buf][sr][sq * 4] = make_ushort4(h0, h1, h2, h3);
        *(ushort4*)&Pl[buf][sr][sq * 4] = make_ushort4(
            f2bf(fa.x - bf2f(h0)), f2bf(fa.y - bf2f(h1)),
            f2bf(fa.z - bf2f(h2)), f2bf(fa.w - bf2f(h3)));
        h0 = f2bf(fb.x); h1 = f2bf(fb.y); h2 = f2bf(fb.z); h3 = f2bf(fb.w);
        *(ushort4*)&Ph[buf][sr + 128][sq * 4] = make_ushort4(h0, h1, h2, h3);
        *(ushort4*)&Pl[buf][sr + 128][sq * 4] = make_ushort4(
            f2bf(fb.x - bf2f(h0)), f2bf(fb.y - bf2f(h1)),
            f2bf(fb.z - bf2f(h2)), f2bf(fb.w - bf2f(h3)));
    };

    const int n0 = w * 16;                      // wave's 16-patch strip
    const int urow = (ln < kC) ? ln : kC;       // A row (zeros for ln>=5)
    f32x4 acc = {0.f, 0.f, 0.f, 0.f};

    load_regs(0);
    write_lds(0);
    __syncthreads();                            // also covers phase-0 u writes
    int cur = 0;
    for (int chunk = 0; chunk < 24; ++chunk) {
        if (chunk < 23) { load_regs(chunk + 1); write_lds(cur ^ 1); }
        const short8v ah  = *(const short8v*)&Uh[urow][chunk * 32 + kq * 8];
        const short8v al_ = *(const short8v*)&Ul[urow][chunk * 32 + kq * 8];
        const short8v bh  = *(const short8v*)&Ph[cur][n0 + ln][kq * 8];
        const short8v bl  = *(const short8v*)&Pl[cur][n0 + ln][kq * 8];
        acc = __builtin_amdgcn_mfma_f32_16x16x32_bf16(al_, bh, acc, 0, 0, 0);
        acc = __builtin_amdgcn_mfma_f32_16x16x32_bf16(ah,  bl, acc, 0, 0, 0);
        acc = __builtin_amdgcn_mfma_f32_16x16x32_bf16(ah,  bh, acc, 0, 0, 0);
        __syncthreads();
        cur ^= 1;
    }
    // D layout: row(c) = kq*4 + reg, col(n-local) = ln
    if (kq == 0) {
        #pragma unroll
        for (int r = 0; r < 4; ++r) simsL[r][n0 + ln] = acc[r];
    } else if (kq == 1) {
        simsL[4][n0 + ln] = acc[0];
    }
    __syncthreads();

    // ---- phase 2: top-2 per cue (first-index tie-break) ----
    if (w < kC) {
        const int c = w;
        float m1 = -3.4e38f, m2 = -3.4e38f; int i1 = 0;
        #pragma unroll
        for (int k = 0; k < 4; ++k) {
            const int n = lane + k * 64;
            const float v = simsL[c][n];
            if (v > m1 || (v == m1 && n < i1)) { m2 = m1; m1 = v; i1 = n; }
            else if (v > m2) m2 = v;
        }
        #pragma unroll
        for (int off = 32; off >= 1; off >>= 1) {
            const float om1 = __shfl_xor(m1, off, 64);
            const int   oi1 = __shfl_xor(i1, off, 64);
            const float om2 = __shfl_xor(m2, off, 64);
            float nm2 = fmaxf(m2, om2);
            if (om1 > m1 || (om1 == m1 && oi1 < i1)) { nm2 = fmaxf(nm2, m1); m1 = om1; i1 = oi1; }
            else nm2 = fmaxf(nm2, om1);
            m2 = nm2;
        }
        if (lane == 0) {
            bestn[c] = i1;
            if (m1 - m2 < kTau) atomicOr(&flags, 1 << c);
        }
    }
    __syncthreads();

    // ---- phase 3: fp64 recheck for flagged cues (block-uniform, rare) ----
    for (int c = 0; c < kC; ++c) {
        if (!(flags & (1 << c))) continue;
        {   // tcb64[j] = cue . W[j] + b[j]
            const float* cuep = &tokens[tb + (size_t)c * kD + lane * 4];
            const float4 cf0 = *(const float4*)&cuep[0];
            const float4 cf1 = *(const float4*)&cuep[256];
            const float4 cf2 = *(const float4*)&cuep[512];
            for (int j = w; j < kD; j += 16) {
                const float* wr = &W[(size_t)j * kD + lane * 4];
                const float4 w0 = *(const float4*)&wr[0];
                const float4 w1 = *(const float4*)&wr[256];
                const float4 w2 = *(const float4*)&wr[512];
                double acc2 = (double)w0.x*cf0.x + (double)w0.y*cf0.y + (double)w0.z*cf0.z + (double)w0.w*cf0.w
                            + (double)w1.x*cf1.x + (double)w1.y*cf1.y + (double)w1.z*cf1.z + (double)w1.w*cf1.w
                            + (double)w2.x*cf2.x + (double)w2.y*cf2.y + (double)w2.z*cf2.z + (double)w2.w*cf2.w;
                #pragma unroll
                for (int off = 32; off >= 1; off >>= 1)
                    acc2 += __shfl_xor(acc2, off, 64);
                if (lane == 0) tcb64[j] = acc2 + (double)bvec[j];
            }
        }
        __syncthreads();
        if (t < kD) {   // u64[i] = sum_j tcb64[j] * W[j][i]
            double acc2 = 0.0;
            for (int j = 0; j < kD; ++j)
                acc2 += tcb64[j] * (double)W[(size_t)j * kD + t];
            u64s[t] = acc2;
        }
        __syncthreads();
        for (int n = w; n < kP; n += 16) {   // fp64 sims, wave-per-patch
            const float* p = &tokens[tb + (size_t)(kC + n) * kD + lane * 4];
            const float4 p0 = *(const float4*)&p[0];
            const float4 p1 = *(const float4*)&p[256];
            const float4 p2 = *(const float4*)&p[512];
            const double* ud = &u64s[lane * 4];
            double acc2 = (double)p0.x*ud[0]   + (double)p0.y*ud[1]   + (double)p0.z*ud[2]   + (double)p0.w*ud[3]
                        + (double)p1.x*ud[256] + (double)p1.y*ud[257] + (double)p1.z*ud[258] + (double)p1.w*ud[259]
                        + (double)p2.x*ud[512] + (double)p2.y*ud[513] + (double)p2.z*ud[514] + (double)p2.w*ud[515];
            #pragma unroll
            for (int off = 32; off >= 1; off >>= 1)
                acc2 += __shfl_xor(acc2, off, 64);
            if (lane == 0) s64[n] = acc2;
        }
        __syncthreads();
        if (w == 0) {   // fp64 argmax, first-index tie-break
            double best = -1.0e300; int bi = 0;
            #pragma unroll
            for (int k = 0; k < 4; ++k) {
                const int n = lane + k * 64;
                const double v = s64[n];
                if (v > best || (v == best && n < bi)) { best = v; bi = n; }
            }
            #pragma unroll
            for (int off = 32; off >= 1; off >>= 1) {
                const double v2 = __shfl_xor(best, off, 64);
                const int    i2 = __shfl_xor(bi, off, 64);
                if (v2 > best || (v2 == best && i2 < bi)) { best = v2; bi = i2; }
            }
            if (lane == 0) bestn[c] = bi;
        }
        __syncthreads();
    }

    // ---- phase 4: ROI means (coalesced over d = t) ----
    if (t < kD) {
        const int d = t;
        #pragma unroll
        for (int c = 0; c < kC; ++c) {
            const int nn = bestn[c];
            const int h = nn >> 4, ww = nn & 15;
            const int rlo = max(h - 1, 0), rhi = min(h + 1, kG - 1);
            const int clo = max(ww - 1, 0), chi = min(ww + 1, kG - 1);
            float sum = 0.f;
            for (int rr = rlo; rr <= rhi; ++rr)
                for (int cc = clo; cc <= chi; ++cc)
                    sum += tokens[tb + (size_t)(kC + rr * kG + cc) * kD + d];
            roi[((size_t)b * kC + c) * kD + d] = sum / (float)((rhi - rlo + 1) * (chi - clo + 1));
        }
    }
}

// ============ Knorm: row-wise L2 normalize (in-place on out) ============
__global__ __launch_bounds__(256)
void knorm(float* __restrict__ out)
{
    __shared__ float wsum[4];
    const int row = blockIdx.x, t = threadIdx.x;
    float* p = out + (size_t)row * kD;
    const float x0 = p[t], x1 = p[t + 256], x2 = p[t + 512];
    float ss = x0 * x0 + x1 * x1 + x2 * x2;
    #pragma unroll
    for (int off = 32; off >= 1; off >>= 1) ss += __shfl_down(ss, off, 64);
    if ((t & 63) == 0) wsum[t >> 6] = ss;
    __syncthreads();
    const float tot = wsum[0] + wsum[1] + wsum[2] + wsum[3];
    const float nrm = fmaxf(sqrtf(tot), 1e-12f);
    p[t] = x0 / nrm; p[t + 256] = x1 / nrm; p[t + 512] = x2 / nrm;
}

extern "C" void kernel_launch(void* const* d_in, const int* in_sizes, int n_in,
                              void* d_out, int out_size, void* d_ws, size_t ws_size,
                              hipStream_t stream) {
    const float* tokens = (const float*)d_in[0];
    const float* W      = (const float*)d_in[1];
    const float* bvec   = (const float*)d_in[2];
    float* out = (float*)d_out;
    float* ws = (float*)d_ws;
    float* tcb   = ws;
    float* u_all = ws + 983040;
    float* roi   = ws + 1966080;
    ushort_t* wsb = (ushort_t*)(ws + 2949120);
    ushort_t* Wb_hi = wsb;
    ushort_t* Wb_lo = wsb + 589824;
    ushort_t* Wt_hi = wsb + 1179648;
    ushort_t* Wt_lo = wsb + 1769472;

    kprep<<<dim3(576), 256, 0, stream>>>(W, Wb_hi, Wb_lo, Wt_hi, Wt_lo);
    kmm<0><<<dim3(40, 12), 256, 0, stream>>>(tokens, Wb_hi, Wb_lo, bvec, nullptr, tcb, out);
    kmm<1><<<dim3(40, 12), 256, 0, stream>>>(tokens, Wt_hi, Wt_lo, bvec, tcb, u_all, nullptr);
    ksel<<<dim3(256), 1024, 0, stream>>>(tokens, W, bvec, u_all, roi);
    kmm<2><<<dim3(40, 12), 256, 0, stream>>>(tokens, Wb_hi, Wb_lo, bvec, roi, out, nullptr);
    knorm<<<dim3(2560), 256, 0, stream>>>(out);
}